// Round 2
// baseline (30015.921 us; speedup 1.0000x reference)
//
#include <hip/hip_runtime.h>
#include <hip/hip_bf16.h>

// EnsembleRSSM observe scan: B=256, T=64, STOCH=32, DETER=1024, HIDDEN=1024,
// EMBED=1536, ACT=6, ENS=5. Sequential over T; parallel over B.
// v3: ONE persistent kernel for the whole T-loop (768 blocks, 3/CU, plain
// launch with exact-occupancy co-residency), custom 2-level device barrier
// replacing 256 kernel boundaries. Phase algorithms identical to v2, with
// heads-obs split 8-way so the heads phase fills all 768 blocks.

#define B_ 256
#define T_ 64
#define ACT_ 6
#define EMBED_ 1536
#define OUTW_ 1216
#define NBLK 768

typedef __attribute__((ext_vector_type(8))) short bf16x8;
typedef __attribute__((ext_vector_type(4))) float f32x4;

__device__ inline unsigned short f2bf(float x) {
    union { float f; unsigned int u; } v; v.f = x;
    unsigned int r = v.u + 0x7fffu + ((v.u >> 16) & 1u);
    return (unsigned short)(r >> 16);
}
__device__ inline float softplus_f(float x) { return x > 20.f ? x : log1pf(expf(x)); }
__device__ inline float sigmoid_f(float x) { return 1.f / (1.f + expf(-x)); }
__device__ inline float elu_f(float x) { return x > 0.f ? x : expm1f(x); }

// ---------------- transpose + fp32->bf16 convert: dst[n][k] = src[k][n] ----
__global__ __launch_bounds__(256)
void k_transpose_cvt(const float* __restrict__ src, unsigned short* __restrict__ dst,
                     int K, int N) {
    __shared__ float tile[32][33];
    size_t off = (size_t)blockIdx.z * K * N;
    src += off; dst += off;
    int n0 = blockIdx.x * 32, k0 = blockIdx.y * 32;
    int tx = threadIdx.x, ty = threadIdx.y;
    for (int i = ty; i < 32; i += 8) tile[i][tx] = src[(size_t)(k0 + i) * N + n0 + tx];
    __syncthreads();
    for (int i = ty; i < 32; i += 8) dst[(size_t)(n0 + i) * K + k0 + tx] = f2bf(tile[tx][i]);
}

// ---------------- MFMA tile with depth-2 register prefetch -----------------
template<int MF, int NF, int KI>
__device__ inline void mfma_tile_db(const unsigned short* __restrict__ A, int lda,
                                    const unsigned short* __restrict__ Bt, int ldb,
                                    int row0, int col0, f32x4 acc[MF][NF]) {
    int lane = threadIdx.x & 63;
    int lr = lane & 15, q = lane >> 4;
    const unsigned short* ap = A + (size_t)(row0 + lr) * lda + q * 8;
    const unsigned short* bp = Bt + (size_t)(col0 + lr) * ldb + q * 8;
    bf16x8 a0[MF], b0[NF], a1[MF], b1[NF], a2[MF], b2[NF];
    auto ld = [&](bf16x8 (&av)[MF], bf16x8 (&bv)[NF], int kk) {
#pragma unroll
        for (int i = 0; i < MF; i++) av[i] = *(const bf16x8*)(ap + (size_t)i * 16 * lda + kk);
#pragma unroll
        for (int j = 0; j < NF; j++) bv[j] = *(const bf16x8*)(bp + (size_t)j * 16 * ldb + kk);
    };
    auto mm = [&](bf16x8 (&av)[MF], bf16x8 (&bv)[NF]) {
#pragma unroll
        for (int i = 0; i < MF; i++)
#pragma unroll
            for (int j = 0; j < NF; j++)
                acc[i][j] = __builtin_amdgcn_mfma_f32_16x16x32_bf16(av[i], bv[j], acc[i][j], 0, 0, 0);
    };
    ld(a0, b0, 0);
    if (KI > 1) ld(a1, b1, 32);
#pragma unroll
    for (int s = 0; s < KI; s++) {
        if (s + 2 < KI) {
            const int ml = (s + 2) % 3;
            if (ml == 0) ld(a0, b0, (s + 2) * 32);
            else if (ml == 1) ld(a1, b1, (s + 2) * 32);
            else ld(a2, b2, (s + 2) * 32);
        }
        const int mc = s % 3;
        if (mc == 0) mm(a0, b0);
        else if (mc == 1) mm(a1, b1);
        else mm(a2, b2);
    }
}

// ---------------- persistent-kernel parameters -----------------------------
struct RssmParams {
    const float* embed;
    const float* action;
    const float* eps_post;
    const float* eps_prior;
    const unsigned char* is_first;
    const int* ens_idx;
    const float* b_gru;
    const float* ln_g;
    const float* ln_b;
    const float* W_inp;
    const float* b_inp;
    const float* b_obs;
    const float* b_ens;
    const float* Wod;   // W_obs_dist [1024][64]
    const float* bod;
    const float* Wed;   // W_ens_dist [5][1024][64]
    const float* bed;
    const unsigned short* Wt_gru;  // [3072][2048]
    const unsigned short* Wt_obs;  // [1024][2560]
    const unsigned short* Wt_ens;  // [5][1024][1024]
    float* deter;
    float* deter_m;
    float* Gp;          // [4][256][3072] f32; aliased by h_part[4]/xo_part[8] [256][1024]
    float* out;
    unsigned short* xcat;    // [256][2048]
    unsigned short* dcat;    // [256][2560]
    unsigned short* dnew_bf; // [256][1024]
    unsigned* bar;      // barrier block (zeroed)
};

// ---------------- device-wide barrier (2-level, sense via generation) ------
// bar layout (unsigned, 256B-strided to spread channels):
//   bar[sub*64] for sub=0..7  : sub-counters (96 arrivals each)
//   bar[512]                  : root counter (8 arrivals)
//   bar[576]                  : generation
__device__ inline void gbar(unsigned* bar) {
    __syncthreads();   // drains each wave's stores (vmcnt) to own L2
    if (threadIdx.x == 0) {
        __threadfence();   // release: write back L2 so other XCDs can see
        unsigned* gen = bar + 576;
        unsigned g = __hip_atomic_load(gen, __ATOMIC_RELAXED, __HIP_MEMORY_SCOPE_AGENT);
        unsigned sub = blockIdx.x & 7u;
        unsigned prev = __hip_atomic_fetch_add(bar + sub * 64, 1u,
                                               __ATOMIC_ACQ_REL, __HIP_MEMORY_SCOPE_AGENT);
        if (prev == (NBLK / 8) - 1) {
            __hip_atomic_store(bar + sub * 64, 0u, __ATOMIC_RELEASE, __HIP_MEMORY_SCOPE_AGENT);
            unsigned p2 = __hip_atomic_fetch_add(bar + 512, 1u,
                                                 __ATOMIC_ACQ_REL, __HIP_MEMORY_SCOPE_AGENT);
            if (p2 == 7u) {
                __hip_atomic_store(bar + 512, 0u, __ATOMIC_RELEASE, __HIP_MEMORY_SCOPE_AGENT);
                __hip_atomic_store(gen, g + 1u, __ATOMIC_RELEASE, __HIP_MEMORY_SCOPE_AGENT);
            }
        }
        int guard = 0;
        while (__hip_atomic_load(gen, __ATOMIC_RELAXED, __HIP_MEMORY_SCOPE_AGENT) == g) {
            __builtin_amdgcn_s_sleep(2);
            if (++guard > 4000000) break;   // failsafe: wrong-result instead of hang
        }
        __threadfence();   // acquire: invalidate L1/L2 so we read fresh data
    }
    __syncthreads();
}

// ---------------- the persistent scan kernel -------------------------------
__global__ __launch_bounds__(256, 3)
void rssm_persistent(RssmParams P) {
    const int id = blockIdx.x;
    const int tid = threadIdx.x;
    const int wave = tid >> 6, lane = tid & 63;
    const int lr = lane & 15, q = lane >> 4;

    // shared scratch union: gates {r1[4],r2[4],mean,rstd} / dist-prep layout
    __shared__ float smem[2472];
    float* s_h     = smem;          // [1024]
    float* s_xo    = smem + 1024;   // [1024]
    float* s_par   = smem + 2048;   // [256]
    float* s_acc   = smem + 2304;   // [128]
    float* s_stoch = smem + 2432;   // [32]
    float* s_am    = smem + 2464;   // [8]
    float* g_r1    = smem;          // gates aliases (disjoint in time)
    float* g_r2    = smem + 4;
    float* g_ms    = smem + 8;      // [0]=mean [1]=rstd

    float* h_part  = P.Gp;                          // [4][256][1024]
    float* xo_part = P.Gp + (size_t)4 * B_ * 1024;  // [8][256][1024]

    // ---------------- phase bodies as lambdas ----------------
    auto gru_phase = [&]() {
        int x = id % 96, y = (id / 96) & 1, z = id / 192;  // 96*2*4 = 768
        int row0 = y * 128 + wave * 32, col0 = x * 32;
        f32x4 acc[2][2];
#pragma unroll
        for (int i = 0; i < 2; i++)
#pragma unroll
            for (int j = 0; j < 2; j++) { f32x4 zz = {0.f,0.f,0.f,0.f}; acc[i][j] = zz; }
        mfma_tile_db<2, 2, 16>(P.xcat + z * 512, 2048, P.Wt_gru + z * 512, 2048,
                               row0, col0, acc);
        float* dst = P.Gp + (size_t)z * (B_ * 3072);
#pragma unroll
        for (int i = 0; i < 2; i++)
#pragma unroll
            for (int j = 0; j < 2; j++)
#pragma unroll
                for (int r = 0; r < 4; r++) {
                    int row = row0 + i * 16 + q * 4 + r;
                    int col = col0 + j * 16 + lr;
                    dst[(size_t)row * 3072 + col] = acc[i][j][r];
                }
    };

    auto gates_phase = [&](int t) {
        int b = id;
        float g0[4], g1[4], g2[4];
        float s1 = 0.f, s2 = 0.f;
        const float* base = P.Gp + (size_t)b * 3072;
#pragma unroll
        for (int jj = 0; jj < 4; jj++) {
            int j = tid + jj * 256;
            float a0 = P.b_gru[j], a1 = P.b_gru[j + 1024], a2 = P.b_gru[j + 2048];
#pragma unroll
            for (int s = 0; s < 4; s++) {
                const float* p = base + (size_t)s * (B_ * 3072) + j;
                a0 += p[0]; a1 += p[1024]; a2 += p[2048];
            }
            g0[jj] = a0; g1[jj] = a1; g2[jj] = a2;
            s1 += a0 + a1 + a2;
            s2 += a0 * a0 + a1 * a1 + a2 * a2;
        }
#pragma unroll
        for (int o = 32; o > 0; o >>= 1) { s1 += __shfl_down(s1, o, 64); s2 += __shfl_down(s2, o, 64); }
        if ((tid & 63) == 0) { g_r1[wave] = s1; g_r2[wave] = s2; }
        __syncthreads();
        if (tid == 0) {
            float a = 0.f, c = 0.f;
            for (int i = 0; i < 4; i++) { a += g_r1[i]; c += g_r2[i]; }
            float mean = a / 3072.f;
            float var = c / 3072.f - mean * mean;
            g_ms[0] = mean; g_ms[1] = rsqrtf(var + 1e-5f);
        }
        __syncthreads();
        float mean = g_ms[0], rstd = g_ms[1];
#pragma unroll
        for (int jj = 0; jj < 4; jj++) {
            int j = tid + jj * 256;
            float n0 = (g0[jj] - mean) * rstd * P.ln_g[j] + P.ln_b[j];
            float n1 = (g1[jj] - mean) * rstd * P.ln_g[j + 1024] + P.ln_b[j + 1024];
            float n2 = (g2[jj] - mean) * rstd * P.ln_g[j + 2048] + P.ln_b[j + 2048];
            float reset = sigmoid_f(n0);
            float cand = tanhf(reset * n1);
            float upd = sigmoid_f(n2 - 1.f);   // UPDATE_BIAS = -1
            float dn = upd * cand + (1.f - upd) * P.deter_m[(size_t)b * 1024 + j];
            P.deter[(size_t)b * 1024 + j] = dn;
            P.dnew_bf[(size_t)b * 1024 + j] = f2bf(dn);
            P.dcat[(size_t)b * 2560 + j] = f2bf(dn);
            P.out[((size_t)b * T_ + t) * OUTW_ + 192 + j] = dn;
        }
        __syncthreads();   // protect smem before next phase reuse
    };

    auto heads_phase = [&](int t) {
        int x = id & 31, y = (id >> 5) & 1, z = id >> 6;   // 32*2*12 = 768
        int row0 = y * 128 + wave * 32, col0 = x * 32;
        f32x4 acc[2][2];
#pragma unroll
        for (int i = 0; i < 2; i++)
#pragma unroll
            for (int j = 0; j < 2; j++) { f32x4 zz = {0.f,0.f,0.f,0.f}; acc[i][j] = zz; }
        float* dst;
        if (z < 4) {   // ens head: K = 4 x 256
            int e = P.ens_idx[t];
            mfma_tile_db<2, 2, 8>(P.dnew_bf + z * 256, 1024,
                                  P.Wt_ens + (size_t)e * 1024 * 1024 + z * 256, 1024,
                                  row0, col0, acc);
            dst = h_part + (size_t)z * (B_ * 1024);
        } else {       // obs head: K = 8 x 320
            int zz = z - 4;
            mfma_tile_db<2, 2, 10>(P.dcat + zz * 320, 2560, P.Wt_obs + zz * 320, 2560,
                                   row0, col0, acc);
            dst = xo_part + (size_t)zz * (B_ * 1024);
        }
#pragma unroll
        for (int i = 0; i < 2; i++)
#pragma unroll
            for (int j = 0; j < 2; j++)
#pragma unroll
                for (int r = 0; r < 4; r++) {
                    int row = row0 + i * 16 + q * 4 + r;
                    int col = col0 + j * 16 + lr;
                    dst[(size_t)row * 1024 + col] = acc[i][j][r];
                }
    };

    auto prep_phase = [&](int t) {
        int b = id;
        if (t >= 0) {
            int e = P.ens_idx[t];
            {   // sum partials + bias, elu -> LDS (4 f32/thread)
                int i = tid * 4;
                const float* hb = h_part + (size_t)b * 1024 + i;
                f32x4 hv = *(const f32x4*)(hb);
#pragma unroll
                for (int s = 1; s < 4; s++) hv += *(const f32x4*)(hb + (size_t)s * 256 * 1024);
                f32x4 hbia = *(const f32x4*)(P.b_ens + (size_t)e * 1024 + i);
                const float* xb = xo_part + (size_t)b * 1024 + i;
                f32x4 xv = *(const f32x4*)(xb);
#pragma unroll
                for (int s = 1; s < 8; s++) xv += *(const f32x4*)(xb + (size_t)s * 256 * 1024);
                f32x4 xbia = *(const f32x4*)(P.b_obs + i);
#pragma unroll
                for (int r = 0; r < 4; r++) {
                    s_h[i + r] = elu_f(hv[r] + hbia[r]);
                    s_xo[i + r] = elu_f(xv[r] + xbia[r]);
                }
            }
            __syncthreads();
            {   // dist matmuls: 128 output cols x 2 K-halves
                int kh = tid >> 7, c = tid & 127;
                int k0 = kh * 512;
                float acc = 0.f;
                if (c < 64) {
                    const float* W = P.Wed + (size_t)e * 65536 + c;
                    for (int k = 0; k < 512; k++) acc += s_h[k0 + k] * W[(size_t)(k0 + k) * 64];
                } else {
                    const float* W = P.Wod + (c - 64);
                    for (int k = 0; k < 512; k++) acc += s_xo[k0 + k] * W[(size_t)(k0 + k) * 64];
                }
                s_par[tid] = acc;
            }
            __syncthreads();
            if (tid < 128) {
                int c = tid & 63;
                float acc = s_par[tid] + s_par[tid + 128];
                acc += (tid < 64) ? P.bed[e * 64 + c] : P.bod[c];
                s_acc[tid] = acc;
            }
            __syncthreads();
            if (tid < 32) {
                float pm = s_acc[tid];
                float ps = softplus_f(s_acc[32 + tid]) + 0.1f;
                float om = s_acc[64 + tid];
                float os = softplus_f(s_acc[96 + tid]) + 0.1f;
                size_t bt = (size_t)b * T_ + t;
                float prior = pm + ps * P.eps_prior[bt * 32 + tid];
                float post = om + os * P.eps_post[bt * 32 + tid];
                float* o = P.out + bt * OUTW_;
                o[tid] = om; o[32 + tid] = os; o[64 + tid] = post;
                o[96 + tid] = pm; o[128 + tid] = ps; o[160 + tid] = prior;
                s_stoch[tid] = post;
            }
        } else {
            if (tid < 32) s_stoch[tid] = 0.f;   // initial carry
        }
        int tn = t + 1;
        if (tn < T_) {
            __syncthreads();
            float m = P.is_first[b * T_ + tn] ? 0.f : 1.f;
            if (tid < ACT_) s_am[tid] = P.action[((size_t)b * T_ + tn) * ACT_ + tid] * m;
            __syncthreads();
            for (int n = tid; n < 1024; n += 256) {
                float sacc = 0.f;
#pragma unroll
                for (int k = 0; k < 32; k++) sacc += s_stoch[k] * P.W_inp[k * 1024 + n];
                float a = P.b_inp[n] + m * sacc;
#pragma unroll
                for (int k = 0; k < ACT_; k++) a += s_am[k] * P.W_inp[(32 + k) * 1024 + n];
                P.xcat[(size_t)b * 2048 + n] = f2bf(elu_f(a));
                float dv = (t >= 0) ? P.deter[(size_t)b * 1024 + n] : 0.f;
                float dm = dv * m;
                P.deter_m[(size_t)b * 1024 + n] = dm;
                P.xcat[(size_t)b * 2048 + 1024 + n] = f2bf(dm);
            }
            for (int j = tid; j < EMBED_; j += 256)
                P.dcat[(size_t)b * 2560 + 1024 + j] =
                    f2bf(P.embed[((size_t)b * T_ + tn) * EMBED_ + j]);
        }
        __syncthreads();
    };

    // ---------------- the scan ----------------
    if (id < B_) prep_phase(-1);
    gbar(P.bar);
    for (int t = 0; t < T_; ++t) {
        gru_phase();
        gbar(P.bar);
        if (id < B_) gates_phase(t);
        gbar(P.bar);
        heads_phase(t);
        gbar(P.bar);
        if (id < B_) prep_phase(t);
        gbar(P.bar);
    }
}

extern "C" void kernel_launch(void* const* d_in, const int* in_sizes, int n_in,
                              void* d_out, int out_size, void* d_ws, size_t ws_size,
                              hipStream_t stream) {
    const float* embed      = (const float*)d_in[0];
    const float* action     = (const float*)d_in[1];
    const float* eps_post   = (const float*)d_in[2];
    const float* eps_prior  = (const float*)d_in[3];
    const unsigned char* is_first = (const unsigned char*)d_in[4];
    const int* ens_idx      = (const int*)d_in[5];
    const float* W_gru      = (const float*)d_in[6];
    const float* b_gru      = (const float*)d_in[7];
    const float* ln_g       = (const float*)d_in[8];
    const float* ln_b       = (const float*)d_in[9];
    const float* W_inp      = (const float*)d_in[10];
    const float* b_inp      = (const float*)d_in[11];
    const float* W_obs      = (const float*)d_in[12];
    const float* b_obs      = (const float*)d_in[13];
    const float* W_ens      = (const float*)d_in[14];
    const float* b_ens      = (const float*)d_in[15];
    const float* W_obs_dist = (const float*)d_in[16];
    const float* b_obs_dist = (const float*)d_in[17];
    const float* W_ens_dist = (const float*)d_in[18];
    const float* b_ens_dist = (const float*)d_in[19];
    float* out = (float*)d_out;

    char* p = (char*)d_ws;
    auto take = [&](size_t bytes) -> char* {
        char* r = p;
        p += (bytes + 255) & ~(size_t)255;
        return r;
    };
    unsigned short* Wt_gru = (unsigned short*)take((size_t)3072 * 2048 * 2);
    unsigned short* Wt_obs = (unsigned short*)take((size_t)1024 * 2560 * 2);
    unsigned short* Wt_ens = (unsigned short*)take((size_t)5 * 1024 * 1024 * 2);
    float* deter   = (float*)take((size_t)B_ * 1024 * 4);
    float* deter_m = (float*)take((size_t)B_ * 1024 * 4);
    unsigned short* xcat    = (unsigned short*)take((size_t)B_ * 2048 * 2);
    unsigned short* dcat    = (unsigned short*)take((size_t)B_ * 2560 * 2);
    float* Gp = (float*)take((size_t)4 * B_ * 3072 * 4);   // aliased by heads partials
    unsigned short* dnew_bf = (unsigned short*)take((size_t)B_ * 1024 * 2);
    unsigned* bar = (unsigned*)take(4096);
    if ((size_t)(p - (char*)d_ws) > ws_size) return;

    hipMemsetAsync(bar, 0, 4096, stream);

    k_transpose_cvt<<<dim3(96, 64, 1), dim3(32, 8), 0, stream>>>(W_gru, Wt_gru, 2048, 3072);
    k_transpose_cvt<<<dim3(32, 80, 1), dim3(32, 8), 0, stream>>>(W_obs, Wt_obs, 2560, 1024);
    k_transpose_cvt<<<dim3(32, 32, 5), dim3(32, 8), 0, stream>>>(W_ens, Wt_ens, 1024, 1024);

    RssmParams P;
    P.embed = embed; P.action = action; P.eps_post = eps_post; P.eps_prior = eps_prior;
    P.is_first = is_first; P.ens_idx = ens_idx;
    P.b_gru = b_gru; P.ln_g = ln_g; P.ln_b = ln_b;
    P.W_inp = W_inp; P.b_inp = b_inp; P.b_obs = b_obs; P.b_ens = b_ens;
    P.Wod = W_obs_dist; P.bod = b_obs_dist; P.Wed = W_ens_dist; P.bed = b_ens_dist;
    P.Wt_gru = Wt_gru; P.Wt_obs = Wt_obs; P.Wt_ens = Wt_ens;
    P.deter = deter; P.deter_m = deter_m; P.Gp = Gp; P.out = out;
    P.xcat = xcat; P.dcat = dcat; P.dnew_bf = dnew_bf; P.bar = bar;

    rssm_persistent<<<dim3(NBLK), dim3(256), 0, stream>>>(P);
}

// Round 3
// 4315.785 us; speedup vs baseline: 6.9549x; 6.9549x over previous
//
#include <hip/hip_runtime.h>
#include <hip/hip_bf16.h>

// EnsembleRSSM observe scan: B=256, T=64, STOCH=32, DETER=1024, HIDDEN=1024,
// EMBED=1536, ACT=6, ENS=5. Sequential over T; parallel over B.
// v4: back to multi-kernel (v2 skeleton, verified 4846us). New: the embed half
// of the obs head (embed@W_obs[1024:2560]) is precomputed for ALL t as one big
// MFMA GEMM (Eobs), so the in-loop obs head is K=1024 (chain 20->8 K-slices)
// and the per-step embed copy is gone. Dist chain halved (512-thr prep).

#define B_ 256
#define T_ 64
#define ACT_ 6
#define EMBED_ 1536
#define OUTW_ 1216

typedef __attribute__((ext_vector_type(8))) short bf16x8;
typedef __attribute__((ext_vector_type(4))) float f32x4;

__device__ inline unsigned short f2bf(float x) {
    union { float f; unsigned int u; } v; v.f = x;
    unsigned int r = v.u + 0x7fffu + ((v.u >> 16) & 1u);
    return (unsigned short)(r >> 16);
}
__device__ inline float bf2f(unsigned short h) {
    union { unsigned int u; float f; } v; v.u = ((unsigned int)h) << 16;
    return v.f;
}
__device__ inline float softplus_f(float x) { return x > 20.f ? x : log1pf(expf(x)); }
__device__ inline float sigmoid_f(float x) { return 1.f / (1.f + expf(-x)); }
__device__ inline float elu_f(float x) { return x > 0.f ? x : expm1f(x); }

// ---------------- flat fp32 -> bf16 convert --------------------------------
__global__ __launch_bounds__(256)
void k_convert(const float* __restrict__ src, unsigned short* __restrict__ dst, long n4) {
    // n4 = n/4; each thread converts 4 elems
    for (long i = blockIdx.x * 256 + threadIdx.x; i < n4; i += (long)gridDim.x * 256) {
        f32x4 v = *(const f32x4*)(src + i * 4);
        unsigned short* d = dst + i * 4;
        d[0] = f2bf(v[0]); d[1] = f2bf(v[1]); d[2] = f2bf(v[2]); d[3] = f2bf(v[3]);
    }
}

// ---------------- transpose + fp32->bf16 convert: dst[n][k] = src[k][n] ----
__global__ __launch_bounds__(256)
void k_transpose_cvt(const float* __restrict__ src, unsigned short* __restrict__ dst,
                     int K, int N) {
    __shared__ float tile[32][33];
    size_t off = (size_t)blockIdx.z * K * N;
    src += off; dst += off;
    int n0 = blockIdx.x * 32, k0 = blockIdx.y * 32;
    int tx = threadIdx.x, ty = threadIdx.y;
    for (int i = ty; i < 32; i += 8) tile[i][tx] = src[(size_t)(k0 + i) * N + n0 + tx];
    __syncthreads();
    for (int i = ty; i < 32; i += 8) dst[(size_t)(n0 + i) * K + k0 + tx] = f2bf(tile[tx][i]);
}

// ---------------- MFMA tile with depth-2 register prefetch -----------------
template<int MF, int NF, int KI>
__device__ inline void mfma_tile_db(const unsigned short* __restrict__ A, int lda,
                                    const unsigned short* __restrict__ Bt, int ldb,
                                    int row0, int col0, f32x4 acc[MF][NF]) {
    int lane = threadIdx.x & 63;
    int lr = lane & 15, q = lane >> 4;
    const unsigned short* ap = A + (size_t)(row0 + lr) * lda + q * 8;
    const unsigned short* bp = Bt + (size_t)(col0 + lr) * ldb + q * 8;
    bf16x8 a0[MF], b0[NF], a1[MF], b1[NF], a2[MF], b2[NF];
    auto ld = [&](bf16x8 (&av)[MF], bf16x8 (&bv)[NF], int kk) {
#pragma unroll
        for (int i = 0; i < MF; i++) av[i] = *(const bf16x8*)(ap + (size_t)i * 16 * lda + kk);
#pragma unroll
        for (int j = 0; j < NF; j++) bv[j] = *(const bf16x8*)(bp + (size_t)j * 16 * ldb + kk);
    };
    auto mm = [&](bf16x8 (&av)[MF], bf16x8 (&bv)[NF]) {
#pragma unroll
        for (int i = 0; i < MF; i++)
#pragma unroll
            for (int j = 0; j < NF; j++)
                acc[i][j] = __builtin_amdgcn_mfma_f32_16x16x32_bf16(av[i], bv[j], acc[i][j], 0, 0, 0);
    };
    ld(a0, b0, 0);
    if (KI > 1) ld(a1, b1, 32);
#pragma unroll
    for (int s = 0; s < KI; s++) {
        if (s + 2 < KI) {
            const int ml = (s + 2) % 3;
            if (ml == 0) ld(a0, b0, (s + 2) * 32);
            else if (ml == 1) ld(a1, b1, (s + 2) * 32);
            else ld(a2, b2, (s + 2) * 32);
        }
        const int mc = s % 3;
        if (mc == 0) mm(a0, b0);
        else if (mc == 1) mm(a1, b1);
        else mm(a2, b2);
    }
}

// ---------------- Eobs precompute: Eobs[bt][n] = embed_bf[bt] @ W_obs[1024:,:] ----
// grid (32, 128): block = 128 rows x 32 cols, K = 1536 (KI=48).
__global__ __launch_bounds__(256)
void k_eobs(const unsigned short* __restrict__ ebf, const unsigned short* __restrict__ Wt_obs,
            unsigned short* __restrict__ Eobs) {
    int wave = threadIdx.x >> 6, lane = threadIdx.x & 63;
    int row0 = blockIdx.y * 128 + wave * 32, col0 = blockIdx.x * 32;
    f32x4 acc[2][2];
#pragma unroll
    for (int i = 0; i < 2; i++)
#pragma unroll
        for (int j = 0; j < 2; j++) { f32x4 z = {0.f, 0.f, 0.f, 0.f}; acc[i][j] = z; }
    mfma_tile_db<2, 2, 48>(ebf, 1536, Wt_obs + 1024, 2560, row0, col0, acc);
    int lr = lane & 15, q = lane >> 4;
#pragma unroll
    for (int i = 0; i < 2; i++)
#pragma unroll
        for (int j = 0; j < 2; j++)
#pragma unroll
            for (int r = 0; r < 4; r++) {
                int row = row0 + i * 16 + q * 4 + r;
                int col = col0 + j * 16 + lr;
                Eobs[(size_t)row * 1024 + col] = f2bf(acc[i][j][r]);
            }
}

// ---------------- GRU GEMM partials: Gp[ks] = xcat @ W_gru (K-chunk ks) ----
// grid: (96, 2, 4), 256 thr = 4 waves; wave w rows blockIdx.y*128+w*32..
__global__ __launch_bounds__(256)
void k_gru(const unsigned short* __restrict__ xcat, const unsigned short* __restrict__ Wt,
           float* __restrict__ Gp) {
    int wave = threadIdx.x >> 6, lane = threadIdx.x & 63;
    int row0 = blockIdx.y * 128 + wave * 32, col0 = blockIdx.x * 32;
    int ks = blockIdx.z;
    f32x4 acc[2][2];
#pragma unroll
    for (int i = 0; i < 2; i++)
#pragma unroll
        for (int j = 0; j < 2; j++) { f32x4 z = {0.f, 0.f, 0.f, 0.f}; acc[i][j] = z; }
    mfma_tile_db<2, 2, 16>(xcat + ks * 512, 2048, Wt + ks * 512, 2048, row0, col0, acc);
    float* dst = Gp + (size_t)ks * (256 * 3072);
    int lr = lane & 15, q = lane >> 4;
#pragma unroll
    for (int i = 0; i < 2; i++)
#pragma unroll
        for (int j = 0; j < 2; j++)
#pragma unroll
            for (int r = 0; r < 4; r++) {
                int row = row0 + i * 16 + q * 4 + r;
                int col = col0 + j * 16 + lr;
                dst[(size_t)row * 3072 + col] = acc[i][j][r];
            }
}

// ---------------- LayerNorm + GRU gates, one block (1024 thr) per row ------
__global__ __launch_bounds__(1024)
void k_gates(int t, const float* __restrict__ Gp, const float* __restrict__ b_gru,
             const float* __restrict__ ln_g, const float* __restrict__ ln_b,
             const float* __restrict__ deter_m, float* __restrict__ deter,
             unsigned short* __restrict__ dnew_bf, float* __restrict__ out) {
    int b = blockIdx.x, j = threadIdx.x;
    size_t base = (size_t)b * 3072 + j;
    float g0 = b_gru[j], g1 = b_gru[j + 1024], g2 = b_gru[j + 2048];
#pragma unroll
    for (int s = 0; s < 4; s++) {
        const float* p = Gp + (size_t)s * (256 * 3072) + base;
        g0 += p[0]; g1 += p[1024]; g2 += p[2048];
    }
    float s1 = g0 + g1 + g2;
    float s2 = g0 * g0 + g1 * g1 + g2 * g2;
#pragma unroll
    for (int o = 32; o > 0; o >>= 1) { s1 += __shfl_down(s1, o, 64); s2 += __shfl_down(s2, o, 64); }
    __shared__ float r1[16], r2[16];
    __shared__ float mean_s, rstd_s;
    int w = j >> 6;
    if ((j & 63) == 0) { r1[w] = s1; r2[w] = s2; }
    __syncthreads();
    if (j == 0) {
        float a = 0.f, c = 0.f;
        for (int i = 0; i < 16; i++) { a += r1[i]; c += r2[i]; }
        float mean = a / 3072.f;
        float var = c / 3072.f - mean * mean;
        mean_s = mean; rstd_s = rsqrtf(var + 1e-5f);
    }
    __syncthreads();
    float mean = mean_s, rstd = rstd_s;
    float n0 = (g0 - mean) * rstd * ln_g[j] + ln_b[j];
    float n1 = (g1 - mean) * rstd * ln_g[j + 1024] + ln_b[j + 1024];
    float n2 = (g2 - mean) * rstd * ln_g[j + 2048] + ln_b[j + 2048];
    float reset = sigmoid_f(n0);
    float cand = tanhf(reset * n1);
    float upd = sigmoid_f(n2 - 1.f);   // UPDATE_BIAS = -1
    float dn = upd * cand + (1.f - upd) * deter_m[(size_t)b * 1024 + j];
    deter[(size_t)b * 1024 + j] = dn;
    dnew_bf[(size_t)b * 1024 + j] = f2bf(dn);
    out[((size_t)b * T_ + t) * OUTW_ + 192 + j] = dn;
}

// ---------------- heads GEMM partials ---------------------------------------
// z<4:  h_part[z]    = dnew @ W_ens[idx] (K-chunk z*256, len 256)
// z>=4: xo_part[z-4] = dnew @ W_obs[:1024,:] (K-chunk (z-4)*256, len 256)
// grid: (32, 2, 8), 256 thr. All chains KI=8. Bias/elu/Eobs added in prep.
__global__ __launch_bounds__(256)
void k_heads(int t, const int* __restrict__ ens_idx,
             const unsigned short* __restrict__ dnew_bf,
             const unsigned short* __restrict__ Wt_ens, const unsigned short* __restrict__ Wt_obs,
             float* __restrict__ h_part, float* __restrict__ xo_part) {
    int wave = threadIdx.x >> 6, lane = threadIdx.x & 63;
    int row0 = blockIdx.y * 128 + wave * 32, col0 = blockIdx.x * 32;
    int z = blockIdx.z;
    f32x4 acc[2][2];
#pragma unroll
    for (int i = 0; i < 2; i++)
#pragma unroll
        for (int j = 0; j < 2; j++) { f32x4 zz = {0.f, 0.f, 0.f, 0.f}; acc[i][j] = zz; }
    float* dst;
    if (z < 4) {
        int e = ens_idx[t];
        mfma_tile_db<2, 2, 8>(dnew_bf + z * 256, 1024,
                              Wt_ens + (size_t)e * 1024 * 1024 + z * 256, 1024, row0, col0, acc);
        dst = h_part + (size_t)z * (256 * 1024);
    } else {
        int zz = z - 4;
        mfma_tile_db<2, 2, 8>(dnew_bf + zz * 256, 1024,
                              Wt_obs + zz * 256, 2560, row0, col0, acc);
        dst = xo_part + (size_t)zz * (256 * 1024);
    }
    int lr = lane & 15, q = lane >> 4;
#pragma unroll
    for (int i = 0; i < 2; i++)
#pragma unroll
        for (int j = 0; j < 2; j++)
#pragma unroll
            for (int r = 0; r < 4; r++) {
                int row = row0 + i * 16 + q * 4 + r;
                int col = col0 + j * 16 + lr;
                dst[(size_t)row * 1024 + col] = acc[i][j][r];
            }
}

// ---------------- dist layers + output + NEXT-step input prep --------------
// One block (512 thr) per batch row. t = -1 => prep only (for t=0).
__global__ __launch_bounds__(512)
void k_dist_prep(int t,
                 const float* __restrict__ eps_post, const float* __restrict__ eps_prior,
                 const int* __restrict__ ens_idx,
                 const float* __restrict__ Wed, const float* __restrict__ bed,
                 const float* __restrict__ Wod, const float* __restrict__ bod,
                 const float* __restrict__ h_part, const float* __restrict__ xo_part,
                 const unsigned short* __restrict__ Eobs,
                 const float* __restrict__ b_ens, const float* __restrict__ b_obs,
                 const float* __restrict__ action,
                 const unsigned char* __restrict__ is_first,
                 const float* __restrict__ W_inp, const float* __restrict__ b_inp,
                 const float* __restrict__ deter,
                 float* __restrict__ deter_m, unsigned short* __restrict__ xcat,
                 float* __restrict__ out) {
    __shared__ float s_h[1024], s_xo[1024], s_par[512], s_acc[128], s_stoch[32], s_am[8];
    int b = blockIdx.x, tid = threadIdx.x;
    if (t >= 0) {
        int e = ens_idx[t];
        {   // sum partials + bias (+Eobs for xo), elu -> LDS (2 f32/thread)
            int i = tid * 2;
            float h0 = b_ens[(size_t)e * 1024 + i], h1 = b_ens[(size_t)e * 1024 + i + 1];
            float x0 = b_obs[i], x1 = b_obs[i + 1];
            size_t bt1024 = ((size_t)b * T_ + (t >= 0 ? t : 0)) * 1024;
            x0 += bf2f(Eobs[bt1024 + i]);
            x1 += bf2f(Eobs[bt1024 + i + 1]);
#pragma unroll
            for (int s = 0; s < 4; s++) {
                const float* hb = h_part + (size_t)s * (256 * 1024) + (size_t)b * 1024 + i;
                h0 += hb[0]; h1 += hb[1];
                const float* xb = xo_part + (size_t)s * (256 * 1024) + (size_t)b * 1024 + i;
                x0 += xb[0]; x1 += xb[1];
            }
            s_h[i] = elu_f(h0); s_h[i + 1] = elu_f(h1);
            s_xo[i] = elu_f(x0); s_xo[i + 1] = elu_f(x1);
        }
        __syncthreads();
        {   // dist matmuls: 128 output cols x 4 K-quarters
            int kq = tid >> 7, c = tid & 127;
            int k0 = kq * 256;
            float acc = 0.f;
            if (c < 64) {
                const float* W = Wed + (size_t)e * 65536 + c;   // [e][k][c], k stride 64
                for (int k = 0; k < 256; k++) acc += s_h[k0 + k] * W[(size_t)(k0 + k) * 64];
            } else {
                const float* W = Wod + (c - 64);
                for (int k = 0; k < 256; k++) acc += s_xo[k0 + k] * W[(size_t)(k0 + k) * 64];
            }
            s_par[tid] = acc;
        }
        __syncthreads();
        if (tid < 128) {
            int c = tid & 63;
            float acc = s_par[tid] + s_par[tid + 128] + s_par[tid + 256] + s_par[tid + 384];
            acc += (tid < 64) ? bed[e * 64 + c] : bod[c];
            s_acc[tid] = acc;
        }
        __syncthreads();
        if (tid < 32) {
            float pm = s_acc[tid];
            float ps = softplus_f(s_acc[32 + tid]) + 0.1f;
            float om = s_acc[64 + tid];
            float os = softplus_f(s_acc[96 + tid]) + 0.1f;
            size_t bt = (size_t)b * T_ + t;
            float prior = pm + ps * eps_prior[bt * 32 + tid];
            float post = om + os * eps_post[bt * 32 + tid];
            float* o = out + bt * OUTW_;
            o[tid] = om; o[32 + tid] = os; o[64 + tid] = post;
            o[96 + tid] = pm; o[128 + tid] = ps; o[160 + tid] = prior;
            s_stoch[tid] = post;
        }
    } else {
        if (tid < 32) s_stoch[tid] = 0.f;   // initial carry
    }
    int tn = t + 1;
    if (tn < T_) {
        __syncthreads();
        float m = is_first[b * T_ + tn] ? 0.f : 1.f;
        if (tid < ACT_) s_am[tid] = action[((size_t)b * T_ + tn) * ACT_ + tid] * m;
        __syncthreads();
        for (int n = tid; n < 1024; n += 512) {
            float sacc = 0.f;
#pragma unroll
            for (int k = 0; k < 32; k++) sacc += s_stoch[k] * W_inp[k * 1024 + n];
            float a = b_inp[n] + m * sacc;
#pragma unroll
            for (int k = 0; k < ACT_; k++) a += s_am[k] * W_inp[(32 + k) * 1024 + n];
            xcat[(size_t)b * 2048 + n] = f2bf(elu_f(a));
            float dv = (t >= 0) ? deter[(size_t)b * 1024 + n] : 0.f;
            float dm = dv * m;
            deter_m[(size_t)b * 1024 + n] = dm;
            xcat[(size_t)b * 2048 + 1024 + n] = f2bf(dm);
        }
    }
}

extern "C" void kernel_launch(void* const* d_in, const int* in_sizes, int n_in,
                              void* d_out, int out_size, void* d_ws, size_t ws_size,
                              hipStream_t stream) {
    const float* embed      = (const float*)d_in[0];
    const float* action     = (const float*)d_in[1];
    const float* eps_post   = (const float*)d_in[2];
    const float* eps_prior  = (const float*)d_in[3];
    const unsigned char* is_first = (const unsigned char*)d_in[4];
    const int* ens_idx      = (const int*)d_in[5];
    const float* W_gru      = (const float*)d_in[6];
    const float* b_gru      = (const float*)d_in[7];
    const float* ln_g       = (const float*)d_in[8];
    const float* ln_b       = (const float*)d_in[9];
    const float* W_inp      = (const float*)d_in[10];
    const float* b_inp      = (const float*)d_in[11];
    const float* W_obs      = (const float*)d_in[12];
    const float* b_obs      = (const float*)d_in[13];
    const float* W_ens      = (const float*)d_in[14];
    const float* b_ens      = (const float*)d_in[15];
    const float* W_obs_dist = (const float*)d_in[16];
    const float* b_obs_dist = (const float*)d_in[17];
    const float* W_ens_dist = (const float*)d_in[18];
    const float* b_ens_dist = (const float*)d_in[19];
    float* out = (float*)d_out;

    char* p = (char*)d_ws;
    auto take = [&](size_t bytes) -> char* {
        char* r = p;
        p += (bytes + 255) & ~(size_t)255;
        return r;
    };
    unsigned short* Wt_gru = (unsigned short*)take((size_t)3072 * 2048 * 2);
    unsigned short* Wt_obs = (unsigned short*)take((size_t)1024 * 2560 * 2);
    unsigned short* Wt_ens = (unsigned short*)take((size_t)5 * 1024 * 1024 * 2);
    float* deter   = (float*)take((size_t)B_ * 1024 * 4);
    float* deter_m = (float*)take((size_t)B_ * 1024 * 4);
    unsigned short* xcat    = (unsigned short*)take((size_t)B_ * 2048 * 2);
    float* Gp = (float*)take((size_t)4 * B_ * 3072 * 4);   // aliased by heads partials
    unsigned short* dnew_bf = (unsigned short*)take((size_t)B_ * 1024 * 2);
    unsigned short* ebf  = (unsigned short*)take((size_t)B_ * T_ * EMBED_ * 2);  // 50 MB
    unsigned short* Eobs = (unsigned short*)take((size_t)B_ * T_ * 1024 * 2);    // 33.5 MB
    if ((size_t)(p - (char*)d_ws) > ws_size) return;  // workspace too small
    // heads partials alias Gp (dead after k_gates):
    float* h_part  = Gp;                            // [4][256][1024]
    float* xo_part = Gp + (size_t)4 * B_ * 1024;    // [4][256][1024]

    // ---- one-off precompute ----
    k_transpose_cvt<<<dim3(96, 64, 1), dim3(32, 8), 0, stream>>>(W_gru, Wt_gru, 2048, 3072);
    k_transpose_cvt<<<dim3(32, 80, 1), dim3(32, 8), 0, stream>>>(W_obs, Wt_obs, 2560, 1024);
    k_transpose_cvt<<<dim3(32, 32, 5), dim3(32, 8), 0, stream>>>(W_ens, Wt_ens, 1024, 1024);
    k_convert<<<dim3(2048), dim3(256), 0, stream>>>(embed, ebf, (long)B_ * T_ * EMBED_ / 4);
    k_eobs<<<dim3(32, 128), dim3(256), 0, stream>>>(ebf, Wt_obs, Eobs);

    // prep step 0 inputs (no memset needed: t<0 path zeroes carries)
    k_dist_prep<<<dim3(B_), dim3(512), 0, stream>>>(-1, eps_post, eps_prior, ens_idx,
        W_ens_dist, b_ens_dist, W_obs_dist, b_obs_dist, h_part, xo_part, Eobs, b_ens, b_obs,
        action, is_first, W_inp, b_inp, deter, deter_m, xcat, out);

    for (int t = 0; t < T_; ++t) {
        k_gru<<<dim3(96, 2, 4), dim3(256), 0, stream>>>(xcat, Wt_gru, Gp);
        k_gates<<<dim3(B_), dim3(1024), 0, stream>>>(t, Gp, b_gru, ln_g, ln_b, deter_m, deter,
                                                     dnew_bf, out);
        k_heads<<<dim3(32, 2, 8), dim3(256), 0, stream>>>(t, ens_idx, dnew_bf,
                                                          Wt_ens, Wt_obs, h_part, xo_part);
        k_dist_prep<<<dim3(B_), dim3(512), 0, stream>>>(t, eps_post, eps_prior, ens_idx,
            W_ens_dist, b_ens_dist, W_obs_dist, b_obs_dist, h_part, xo_part, Eobs, b_ens, b_obs,
            action, is_first, W_inp, b_inp, deter, deter_m, xcat, out);
    }
}